// Round 6
// baseline (213.325 us; speedup 1.0000x reference)
//
#include <hip/hip_runtime.h>
#include <hip/hip_bf16.h>

#define S_LEN 4096
#define HID 768
#define NHEAD 12
#define HL 64

typedef __attribute__((ext_vector_type(8))) short short8;
typedef __attribute__((ext_vector_type(4))) float f32x4;
using bf16 = __hip_bfloat16;

__device__ __forceinline__ void gl2lds16(const void* g, void* l) {
  __builtin_amdgcn_global_load_lds((__attribute__((address_space(1))) void*)(g),
                                   (__attribute__((address_space(3))) void*)(l),
                                   16, 0, 0);
}

__device__ __forceinline__ f32x4 mfma_bf16(short8 a, short8 b, f32x4 c) {
  return __builtin_amdgcn_mfma_f32_16x16x32_bf16(a, b, c, 0, 0, 0);
}

__device__ __forceinline__ void storeC(float* C, long idx, float v) { C[idx] = v; }
__device__ __forceinline__ void storeC(bf16* C, long idx, float v) { C[idx] = __float2bfloat16(v); }

// lgkmcnt(0)-only barrier: drains LDS ops but NOT vmcnt, so global loads /
// LDS-DMA stay in flight across the barrier.
#define BAR() asm volatile("s_waitcnt lgkmcnt(0)\n\ts_barrier" ::: "memory")
// pipeline barriers: drain own LDS reads + all but the newest N*4 (or N*2)
// outstanding vector-memory ops (stage-k done, stage-k+1 still in flight)
#define BAR_VM(n) \
  asm volatile("s_waitcnt vmcnt(" #n ") lgkmcnt(0)\n\ts_barrier" ::: "memory")

// ---------------- fp32 -> bf16 convert (x + 4 weights, fused) ----------------
__global__ __launch_bounds__(256) void cvt_all(
    const float* __restrict__ x, const float* __restrict__ wq,
    const float* __restrict__ wk, const float* __restrict__ wv,
    const float* __restrict__ wfc, bf16* __restrict__ xb, bf16* __restrict__ wqb,
    bf16* __restrict__ wkb, bf16* __restrict__ wvb, bf16* __restrict__ wfcb) {
  const long NX = (long)S_LEN * HID;
  const long NW = (long)HID * HID;
  long i = ((long)blockIdx.x * 256 + threadIdx.x) * 4;
  const float* src;
  bf16* dst;
  long off;
  if (i < NX) {
    src = x; dst = xb; off = i;
  } else {
    long j = i - NX;
    int wsel = (int)(j / NW);
    off = j - (long)wsel * NW;
    src = wsel == 0 ? wq : wsel == 1 ? wk : wsel == 2 ? wv : wfc;
    dst = wsel == 0 ? wqb : wsel == 1 ? wkb : wsel == 2 ? wvb : wfcb;
  }
  float4 v = *(const float4*)(src + off);
  bf16 h0 = __float2bfloat16(v.x), h1 = __float2bfloat16(v.y);
  bf16 h2 = __float2bfloat16(v.z), h3 = __float2bfloat16(v.w);
  ushort4 o;
  o.x = *(unsigned short*)&h0; o.y = *(unsigned short*)&h1;
  o.z = *(unsigned short*)&h2; o.w = *(unsigned short*)&h3;
  *(ushort4*)(dst + off) = o;
}

// -------- pipelined GEMM: C[M x 768] = scale * A[M x 768] * B[768 x 768]^T ----
// 128x128 tile, triple-buffered LDS, one lgkm-only barrier per K-iter with
// vmcnt(4): stage-k drained, stage-k+1 (4 gl2lds/wave) stays in flight across
// the barrier; stage-k+2 issued post-barrier (race-free vs iter-k-1 readers).
template <typename OT>
__global__ __launch_bounds__(256, 3) void gemm_bt(
    const bf16* __restrict__ A, const bf16* __restrict__ B0,
    const bf16* __restrict__ B1, const bf16* __restrict__ B2,
    OT* __restrict__ C0, OT* __restrict__ C1, OT* __restrict__ C2, float qscale) {
  constexpr int K = HID, NK = K / 32;
  __shared__ __align__(16) bf16 As[3][128 * 32];
  __shared__ __align__(16) bf16 Bs[3][128 * 32];
  const int z = blockIdx.z;
  const bf16* B = (z == 0) ? B0 : (z == 1) ? B1 : B2;
  OT* C = (z == 0) ? C0 : (z == 1) ? C1 : C2;
  const float sc = (z == 0) ? qscale : 1.0f;
  const int bm = blockIdx.y, bn = blockIdx.x;
  const int t = threadIdx.x, lane = t & 63, w = t >> 6;
  const int wm = w >> 1, wn = w & 1;
  const int q4 = lane >> 4, c16 = lane & 15;
  const int srow = lane >> 2, scol = (lane & 3) * 8;
  const bf16* Ab = A + (long)bm * 128 * K;
  const bf16* Bb = B + (long)bn * 128 * K;

  auto stage = [&](int k, int buf) {
#pragma unroll
    for (int r = 0; r < 2; ++r) {
      int rowb = r * 64 + w * 16;  // wave-uniform 16-row chunk (1 KB each)
      gl2lds16(Ab + (long)(rowb + srow) * K + k * 32 + scol, &As[buf][rowb * 32]);
      gl2lds16(Bb + (long)(rowb + srow) * K + k * 32 + scol, &Bs[buf][rowb * 32]);
    }
  };

  f32x4 acc[4][4] = {};
  stage(0, 0);
  stage(1, 1);
  for (int k = 0; k < NK; ++k) {
    if (k < NK - 1) BAR_VM(4); else BAR_VM(0);
    if (k + 2 < NK) stage(k + 2, (k + 2) % 3);
    const bf16* Al = As[k % 3];
    const bf16* Bl = Bs[k % 3];
    short8 af[4], bfv[4];
#pragma unroll
    for (int i = 0; i < 4; ++i)
      af[i] = *(const short8*)&Al[(wm * 64 + i * 16 + c16) * 32 + q4 * 8];
#pragma unroll
    for (int j = 0; j < 4; ++j)
      bfv[j] = *(const short8*)&Bl[(wn * 64 + j * 16 + c16) * 32 + q4 * 8];
#pragma unroll
    for (int i = 0; i < 4; ++i)
#pragma unroll
      for (int j = 0; j < 4; ++j)
        acc[i][j] = mfma_bf16(af[i], bfv[j], acc[i][j]);
    // no trailing barrier: buffer k%3 is not rewritten until iter k+1 issues
    // stage(k+3) -> buf (k+3)%3 != k%3; earliest rewrite of k%3 is stage(k+3)
    // at iter k+1, post-barrier, by which time all reads of k are lgkm-drained.
  }
  const long crow0 = (long)bm * 128 + wm * 64;
  const int ccol0 = bn * 128 + wn * 64;
#pragma unroll
  for (int i = 0; i < 4; ++i)
#pragma unroll
    for (int j = 0; j < 4; ++j)
#pragma unroll
      for (int r = 0; r < 4; ++r) {
        long row = crow0 + i * 16 + q4 * 4 + r;
        int col = ccol0 + j * 16 + c16;
        storeC(C, row * HID + col, sc * acc[i][j][r]);
      }
}

// -------- pipelined final GEMM: 64x64 tile, 768 blocks = 3/CU exactly --------
__global__ __launch_bounds__(256, 3) void gemm_fc(const bf16* __restrict__ A,
                                                  const bf16* __restrict__ B,
                                                  float* __restrict__ C) {
  constexpr int NK = HID / 32;
  __shared__ __align__(16) bf16 As[3][64 * 32];
  __shared__ __align__(16) bf16 Bs[3][64 * 32];
  const int bm = blockIdx.y, bn = blockIdx.x;
  const int t = threadIdx.x, lane = t & 63, w = t >> 6;
  const int wm = w >> 1, wn = w & 1;
  const int q4 = lane >> 4, c16 = lane & 15;
  const int srow = lane >> 2, scol = (lane & 3) * 8;
  const bf16* Ab = A + (long)bm * 64 * HID;
  const bf16* Bb = B + (long)bn * 64 * HID;

  auto stage = [&](int k, int buf) {
    // wave w stages 16 rows of A and 16 rows of B (1 gl2lds each)
    gl2lds16(Ab + (long)(w * 16 + srow) * HID + k * 32 + scol,
             &As[buf][w * 16 * 32]);
    gl2lds16(Bb + (long)(w * 16 + srow) * HID + k * 32 + scol,
             &Bs[buf][w * 16 * 32]);
  };

  f32x4 acc[2][2] = {};
  stage(0, 0);
  stage(1, 1);
  for (int k = 0; k < NK; ++k) {
    if (k < NK - 1) BAR_VM(2); else BAR_VM(0);
    if (k + 2 < NK) stage(k + 2, (k + 2) % 3);
    const bf16* Al = As[k % 3];
    const bf16* Bl = Bs[k % 3];
    short8 af[2], bfv[2];
#pragma unroll
    for (int i = 0; i < 2; ++i)
      af[i] = *(const short8*)&Al[(wm * 32 + i * 16 + c16) * 32 + q4 * 8];
#pragma unroll
    for (int j = 0; j < 2; ++j)
      bfv[j] = *(const short8*)&Bl[(wn * 32 + j * 16 + c16) * 32 + q4 * 8];
#pragma unroll
    for (int i = 0; i < 2; ++i)
#pragma unroll
      for (int j = 0; j < 2; ++j)
        acc[i][j] = mfma_bf16(af[i], bfv[j], acc[i][j]);
  }
#pragma unroll
  for (int i = 0; i < 2; ++i)
#pragma unroll
    for (int j = 0; j < 2; ++j)
#pragma unroll
      for (int r = 0; r < 4; ++r) {
        long row = (long)bm * 64 + wm * 32 + i * 16 + q4 * 4 + r;
        int col = bn * 64 + wn * 32 + j * 16 + c16;
        C[row * HID + col] = acc[i][j][r];
      }
}

// ---------------- V transpose: [4096][768] -> [768][4096] ----------------
__global__ __launch_bounds__(256) void transpose_v(const bf16* __restrict__ V,
                                                   bf16* __restrict__ Vt) {
  __shared__ unsigned short tile[64][65];
  const int bs = blockIdx.x * 64;
  const int be = blockIdx.y * 64;
  const int t = threadIdx.x;
#pragma unroll
  for (int p = 0; p < 4; ++p) {
    int i = p * 256 + t;
    int r = i >> 4;
    int c = (i & 15) * 4;
    ushort4 v = *(const ushort4*)((const unsigned short*)V + (long)(bs + r) * HID + be + c);
    tile[r][c] = v.x; tile[r][c + 1] = v.y; tile[r][c + 2] = v.z; tile[r][c + 3] = v.w;
  }
  __syncthreads();
#pragma unroll
  for (int p = 0; p < 4; ++p) {
    int i = p * 256 + t;
    int r = i >> 4;
    int c = (i & 15) * 4;
    ushort4 v;
    v.x = tile[c][r]; v.y = tile[c + 1][r]; v.z = tile[c + 2][r]; v.w = tile[c + 3][r];
    *(ushort4*)((unsigned short*)Vt + (long)(be + r) * S_LEN + bs + c) = v;
  }
}

// ---------------- flash attention v5 (unchanged; 103.8 us baseline) -----------
__global__ __launch_bounds__(256, 3) void flash_attn(const bf16* __restrict__ Q,
                                                     const bf16* __restrict__ Kg,
                                                     const bf16* __restrict__ Vt,
                                                     bf16* __restrict__ O) {
  __shared__ __align__(16) bf16 Ps[2][64 * 128];  // [q][kv-swizzled], 32 KB
  __shared__ float Lred[4][64];
  const int qt = blockIdx.x, h = blockIdx.y;
  const int t = threadIdx.x, lane = t & 63, w = t >> 6;
  const int q4 = lane >> 4, c16 = lane & 15;
  const int s0 = qt * 64;

  short8 qf[2][4];
  {
    const bf16* Qb = Q + (long)(s0 + c16) * HID + h * HL + q4 * 8;
#pragma unroll
    for (int j = 0; j < 4; ++j)
#pragma unroll
      for (int ks = 0; ks < 2; ++ks)
        qf[ks][j] = *(const short8*)(Qb + (long)j * 16 * HID + ks * 32);
  }
  const bf16* kp = Kg + (long)(w * 32 + c16) * HID + h * HL + q4 * 8;
  const bf16* vp = Vt + (long)(h * HL + w * 16 + c16) * S_LEN + q4 * 8;

  float l_part[4] = {0.f, 0.f, 0.f, 0.f};
  f32x4 o_acc[4] = {};
  short8 kf[2][2], vf[4];
#pragma unroll
  for (int rr = 0; rr < 2; ++rr)
#pragma unroll
    for (int ks = 0; ks < 2; ++ks)
      kf[rr][ks] = *(const short8*)(kp + (long)rr * 16 * HID + ks * 32);
#pragma unroll
  for (int kc = 0; kc < 4; ++kc) vf[kc] = *(const short8*)(vp + kc * 32);

  for (int kt = 0; kt < S_LEN / 128; ++kt) {
    bf16* Pb = Ps[kt & 1];
    f32x4 sacc[2][4] = {};
#pragma unroll
    for (int rr = 0; rr < 2; ++rr)
#pragma unroll
      for (int ks = 0; ks < 2; ++ks)
#pragma unroll
        for (int j = 0; j < 4; ++j)
          sacc[rr][j] = mfma_bf16(kf[rr][ks], qf[ks][j], sacc[rr][j]);

    const bf16* kpn = (kt == S_LEN / 128 - 1) ? kp : kp + 128 * HID;
#pragma unroll
    for (int rr = 0; rr < 2; ++rr)
#pragma unroll
      for (int ks = 0; ks < 2; ++ks)
        kf[rr][ks] = *(const short8*)(kpn + (long)rr * 16 * HID + ks * 32);
    kp = kpn;

#pragma unroll
    for (int rr = 0; rr < 2; ++rr) {
      const int wch = ((w * 4 + rr * 2 + (q4 >> 1)));
#pragma unroll
      for (int j = 0; j < 4; ++j) {
        float p0 = __builtin_amdgcn_exp2f(sacc[rr][j][0]);
        float p1 = __builtin_amdgcn_exp2f(sacc[rr][j][1]);
        float p2 = __builtin_amdgcn_exp2f(sacc[rr][j][2]);
        float p3 = __builtin_amdgcn_exp2f(sacc[rr][j][3]);
        l_part[j] += (p0 + p1) + (p2 + p3);
        __hip_bfloat162 a01 = __float22bfloat162_rn(float2{p0, p1});
        __hip_bfloat162 a23 = __float22bfloat162_rn(float2{p2, p3});
        int2 pk;
        pk.x = *(int*)&a01;
        pk.y = *(int*)&a23;
        *(int2*)&Pb[(j * 16 + c16) * 128 + (wch ^ c16) * 8 + (q4 & 1) * 4] = pk;
      }
    }
    BAR();

#pragma unroll
    for (int kc = 0; kc < 4; ++kc) {
#pragma unroll
      for (int j = 0; j < 4; ++j) {
        short8 pf = *(const short8*)&Pb[(j * 16 + c16) * 128 + ((kc * 4 + q4) ^ c16) * 8];
        o_acc[j] = mfma_bf16(vf[kc], pf, o_acc[j]);
      }
    }
    const bf16* vpn = (kt == S_LEN / 128 - 1) ? vp : vp + 128;
#pragma unroll
    for (int kc = 0; kc < 4; ++kc) vf[kc] = *(const short8*)(vpn + kc * 32);
    vp = vpn;
  }

#pragma unroll
  for (int j = 0; j < 4; ++j) {
    float s = l_part[j];
    s += __shfl_xor(s, 16, 64);
    s += __shfl_xor(s, 32, 64);
    Lred[w][j * 16 + c16] = s;
  }
  __syncthreads();
#pragma unroll
  for (int j = 0; j < 4; ++j) {
    int q = j * 16 + c16;
    float lt = Lred[0][q] + Lred[1][q] + Lred[2][q] + Lred[3][q];
    float rl = 1.0f / lt;
    float v0 = o_acc[j][0] * rl, v1 = o_acc[j][1] * rl;
    float v2 = o_acc[j][2] * rl, v3 = o_acc[j][3] * rl;
    bf16 b0 = __float2bfloat16(v0), b1 = __float2bfloat16(v1);
    bf16 b2 = __float2bfloat16(v2), b3 = __float2bfloat16(v3);
    short4 pk;
    pk.x = *(short*)&b0; pk.y = *(short*)&b1; pk.z = *(short*)&b2; pk.w = *(short*)&b3;
    *(short4*)&O[(long)(s0 + q) * HID + h * HL + w * 16 + q4 * 4] = pk;
  }
}

extern "C" void kernel_launch(void* const* d_in, const int* in_sizes, int n_in,
                              void* d_out, int out_size, void* d_ws, size_t ws_size,
                              hipStream_t stream) {
  const float* x = (const float*)d_in[0];
  const float* wq = (const float*)d_in[1];
  const float* wk = (const float*)d_in[2];
  const float* wv = (const float*)d_in[3];
  const float* wfc = (const float*)d_in[4];
  float* out = (float*)d_out;

  const long NBIG = (long)S_LEN * HID * sizeof(bf16);
  const long NWB = (long)HID * HID * sizeof(bf16);
  char* p = (char*)d_ws;
  bf16* xb = (bf16*)p;   p += NBIG;
  bf16* wqb = (bf16*)p;  p += NWB;
  bf16* wkb = (bf16*)p;  p += NWB;
  bf16* wvb = (bf16*)p;  p += NWB;
  bf16* wfcb = (bf16*)p; p += NWB;
  bf16* Qb = (bf16*)p;   p += NBIG;
  bf16* Kb = (bf16*)p;   p += NBIG;
  bf16* Vb = (bf16*)p;   p += NBIG;
  bf16* Vtb = (bf16*)p;  p += NBIG;
  bf16* Ob = (bf16*)p;   p += NBIG;

  const float c1 = 0.125f * 1.44269504088896340736f;  // softmax scale * log2(e)

  const long total4 = ((long)S_LEN * HID + 4L * HID * HID) / 4;
  cvt_all<<<(int)(total4 / 256), 256, 0, stream>>>(x, wq, wk, wv, wfc, xb, wqb, wkb,
                                                   wvb, wfcb);
  gemm_bt<bf16><<<dim3(HID / 128, S_LEN / 128, 3), 256, 0, stream>>>(
      xb, wqb, wkb, wvb, Qb, Kb, Vb, c1);
  transpose_v<<<dim3(S_LEN / 64, HID / 64), 256, 0, stream>>>(Vb, Vtb);
  flash_attn<<<dim3(S_LEN / 64, NHEAD), 256, 0, stream>>>(Qb, Kb, Vtb, Ob);
  gemm_fc<<<dim3(HID / 64, S_LEN / 64), 256, 0, stream>>>(Ob, wfcb, out);
}